// Round 2
// baseline (50.052 us; speedup 1.0000x reference)
//
#include <hip/hip_runtime.h>

// HGate on qubits (0,1,2) of a 13-qubit state, D=2, N=8192, B=4096.
// Rows n = (j<<10)|g for j in [0,8) are combined by an 8-point
// Walsh-Hadamard transform scaled by 2^{-3/2}. Batch dim (4096 f32 per row)
// is contiguous -> float4 vectorized, fully coalesced.
//
// v2: 2 float4 columns per thread (16 loads in flight) + nontemporal
// stores (streaming write-once output, keep L3 for the input).

typedef float f32x4 __attribute__((ext_vector_type(4)));

__global__ __launch_bounds__(256) void hgate8_kernel(const float* __restrict__ x,
                                                     float* __restrict__ y) {
    // 524,288 threads: 1024 groups x 512 column-pairs.
    const unsigned t = blockIdx.x * 256u + threadIdx.x;
    const unsigned c = t & 511u;   // float4 column, thread also does c+512
    const unsigned g = t >> 9;     // low-10-bit row group, 0..1023

    const size_t base0 = (size_t)g * 1024u + c;
    const size_t base1 = base0 + 512u;
    const size_t jstr  = 1048576u;   // 1024 rows * 1024 float4/row

    const f32x4* __restrict__ xv = (const f32x4*)x;
    f32x4* __restrict__ yv = (f32x4*)y;

    f32x4 u[8], w[8];
#pragma unroll
    for (int j = 0; j < 8; ++j) u[j] = xv[base0 + j * jstr];
#pragma unroll
    for (int j = 0; j < 8; ++j) w[j] = xv[base1 + j * jstr];

    const float s = 0.35355339059327379f;  // 2^{-3/2}

    // 8-point FWHT butterfly on v[0..7], scaled, stored nontemporally.
#define FWHT8_STORE(v, base)                                            \
    {                                                                   \
        f32x4 a0 = v[0] + v[1], a1 = v[0] - v[1];                       \
        f32x4 a2 = v[2] + v[3], a3 = v[2] - v[3];                       \
        f32x4 a4 = v[4] + v[5], a5 = v[4] - v[5];                       \
        f32x4 a6 = v[6] + v[7], a7 = v[6] - v[7];                       \
        f32x4 b0 = a0 + a2, b2 = a0 - a2;                               \
        f32x4 b1 = a1 + a3, b3 = a1 - a3;                               \
        f32x4 b4 = a4 + a6, b6 = a4 - a6;                               \
        f32x4 b5 = a5 + a7, b7 = a5 - a7;                               \
        __builtin_nontemporal_store((b0 + b4) * s, &yv[base + 0 * jstr]); \
        __builtin_nontemporal_store((b1 + b5) * s, &yv[base + 1 * jstr]); \
        __builtin_nontemporal_store((b2 + b6) * s, &yv[base + 2 * jstr]); \
        __builtin_nontemporal_store((b3 + b7) * s, &yv[base + 3 * jstr]); \
        __builtin_nontemporal_store((b0 - b4) * s, &yv[base + 4 * jstr]); \
        __builtin_nontemporal_store((b1 - b5) * s, &yv[base + 5 * jstr]); \
        __builtin_nontemporal_store((b2 - b6) * s, &yv[base + 6 * jstr]); \
        __builtin_nontemporal_store((b3 - b7) * s, &yv[base + 7 * jstr]); \
    }

    FWHT8_STORE(u, base0)
    FWHT8_STORE(w, base1)
#undef FWHT8_STORE
}

extern "C" void kernel_launch(void* const* d_in, const int* in_sizes, int n_in,
                              void* d_out, int out_size, void* d_ws, size_t ws_size,
                              hipStream_t stream) {
    const float* x = (const float*)d_in[0];
    // d_in[1] is the 2x2 Hadamard matrix; for D=2 it is exactly
    // [[1,1],[1,-1]]/sqrt(2) (real), hard-coded in the butterfly above.
    float* y = (float*)d_out;

    // 1024 groups * 512 column-pairs = 524,288 threads = 2048 blocks x 256.
    hgate8_kernel<<<2048, 256, 0, stream>>>(x, y);
}

// Round 3
// 46.249 us; speedup vs baseline: 1.0822x; 1.0822x over previous
//
#include <hip/hip_runtime.h>

// HGate on qubits (0,1,2) of a 13-qubit state, D=2, N=8192, B=4096.
// Rows n = (j<<10)|g for j in [0,8) are combined by an 8-point
// Walsh-Hadamard transform scaled by 2^{-3/2}. Batch dim (4096 f32 per row)
// is contiguous -> float4 vectorized, fully coalesced.
//
// v3: round-1 structure (1 float4/thread, 32 VGPR, regular stores) +
// per-block rotation of the load/store issue order across the 8
// 16MiB-strided streams, to decorrelate instantaneous HBM channel
// pressure. Rotation is a wave-uniform switch -> fully unrolled, static
// register indices, no divergence.

typedef float f32x4 __attribute__((ext_vector_type(4)));

__global__ __launch_bounds__(256) void hgate8_kernel(const float* __restrict__ x,
                                                     float* __restrict__ y) {
    // 1,048,576 threads: 1024 groups x 1024 float4 columns.
    const unsigned t   = blockIdx.x * 256u + threadIdx.x;
    const unsigned col = t & 1023u;   // float4 column index, B/4 = 1024
    const unsigned g   = t >> 10;     // low-10-bit row group, 0..1023

    const size_t base = (size_t)g * 1024u + col;
    const size_t jstr = 1048576u;     // 1024 rows * 1024 float4/row

    const f32x4* __restrict__ xv = (const f32x4*)x;
    f32x4* __restrict__ yv = (f32x4*)y;

    f32x4 v0, v1, v2, v3, v4, v5, v6, v7;

    const unsigned rot = blockIdx.x & 7u;  // wave-uniform -> scalar branch

#define LD(j) v##j = xv[base + j * jstr];
#define LOADS(a,b,c,d,e,f,g2,h) { LD(a) LD(b) LD(c) LD(d) LD(e) LD(f) LD(g2) LD(h) }
    switch (rot) {
        case 0: LOADS(0,1,2,3,4,5,6,7) break;
        case 1: LOADS(1,2,3,4,5,6,7,0) break;
        case 2: LOADS(2,3,4,5,6,7,0,1) break;
        case 3: LOADS(3,4,5,6,7,0,1,2) break;
        case 4: LOADS(4,5,6,7,0,1,2,3) break;
        case 5: LOADS(5,6,7,0,1,2,3,4) break;
        case 6: LOADS(6,7,0,1,2,3,4,5) break;
        default: LOADS(7,0,1,2,3,4,5,6) break;
    }
#undef LOADS
#undef LD

    // 8-point FWHT (bit order irrelevant: H on each bit commutes).
    f32x4 a0 = v0 + v1, a1 = v0 - v1;
    f32x4 a2 = v2 + v3, a3 = v2 - v3;
    f32x4 a4 = v4 + v5, a5 = v4 - v5;
    f32x4 a6 = v6 + v7, a7 = v6 - v7;
    f32x4 b0 = a0 + a2, b2 = a0 - a2;
    f32x4 b1 = a1 + a3, b3 = a1 - a3;
    f32x4 b4 = a4 + a6, b6 = a4 - a6;
    f32x4 b5 = a5 + a7, b7 = a5 - a7;

    const float s = 0.35355339059327379f;  // 2^{-3/2}
    f32x4 r0 = (b0 + b4) * s, r4 = (b0 - b4) * s;
    f32x4 r1 = (b1 + b5) * s, r5 = (b1 - b5) * s;
    f32x4 r2 = (b2 + b6) * s, r6 = (b2 - b6) * s;
    f32x4 r3 = (b3 + b7) * s, r7 = (b3 - b7) * s;

#define ST(j) yv[base + j * jstr] = r##j;
#define STORES(a,b,c,d,e,f,g2,h) { ST(a) ST(b) ST(c) ST(d) ST(e) ST(f) ST(g2) ST(h) }
    switch (rot) {
        case 0: STORES(0,1,2,3,4,5,6,7) break;
        case 1: STORES(1,2,3,4,5,6,7,0) break;
        case 2: STORES(2,3,4,5,6,7,0,1) break;
        case 3: STORES(3,4,5,6,7,0,1,2) break;
        case 4: STORES(4,5,6,7,0,1,2,3) break;
        case 5: STORES(5,6,7,0,1,2,3,4) break;
        case 6: STORES(6,7,0,1,2,3,4,5) break;
        default: STORES(7,0,1,2,3,4,5,6) break;
    }
#undef STORES
#undef ST
}

extern "C" void kernel_launch(void* const* d_in, const int* in_sizes, int n_in,
                              void* d_out, int out_size, void* d_ws, size_t ws_size,
                              hipStream_t stream) {
    const float* x = (const float*)d_in[0];
    // d_in[1] is the 2x2 Hadamard matrix; for D=2 it is exactly
    // [[1,1],[1,-1]]/sqrt(2) (real), hard-coded in the butterfly above.
    float* y = (float*)d_out;

    // 1024 groups * 1024 float4 columns = 1,048,576 threads = 4096 blocks x 256.
    hgate8_kernel<<<4096, 256, 0, stream>>>(x, y);
}